// Round 1
// baseline (211.243 us; speedup 1.0000x reference)
//
#include <hip/hip_runtime.h>
#include <hip/hip_bf16.h>

typedef short bf16x8 __attribute__((ext_vector_type(8)));
typedef short s16x4  __attribute__((ext_vector_type(4)));
typedef short s16x8  __attribute__((ext_vector_type(8)));
typedef float f32x4  __attribute__((ext_vector_type(4)));

static __device__ __forceinline__ void async_cp16(const void* g, void* l) {
  __builtin_amdgcn_global_load_lds(
      (const __attribute__((address_space(1))) unsigned int*)g,
      (__attribute__((address_space(3))) unsigned int*)l, 16, 0, 0);
}

static __device__ __forceinline__ unsigned short f2bf_bits(float f) {
  union { __hip_bfloat16 b; unsigned short u; } cv;
  cv.b = __float2bfloat16(f);
  return cv.u;
}

// ---------------- fp32 -> bf16 convert (4 elems/thread, no tail) ----------------
__global__ __launch_bounds__(256) void cvt_f32_to_bf16(const float* __restrict__ in,
                                                       __hip_bfloat16* __restrict__ out) {
  const long i = ((long)blockIdx.x * 256 + threadIdx.x) * 4;
  const float4 v = *(const float4*)(in + i);
  s16x4 o;
  o[0] = (short)f2bf_bits(v.x);
  o[1] = (short)f2bf_bits(v.y);
  o[2] = (short)f2bf_bits(v.z);
  o[3] = (short)f2bf_bits(v.w);
  *(s16x4*)(out + i) = o;
}

// ---------------- NT GEMM: C[m,n] = sum_k A[m,k]*B[n,k] ----------------
// 128x128 tile, BK=32, 4 waves (2x2), 16x16x32 bf16 MFMA, global_load_lds staging.
// MODE 0: fp32 store; MODE 1: bf16 store; MODE 2: fp32 store of (v*scale, masked -> -1e20)
template<int MODE>
__global__ __launch_bounds__(256, 2) void gemm_nt(
    const __hip_bfloat16* __restrict__ A, const __hip_bfloat16* __restrict__ B,
    void* __restrict__ Cv, const int* __restrict__ Mask,
    int lda, int ldb, int ldc, int K, float scale,
    long sAb, long sBb, long sCb, long sMb)
{
  __shared__ __hip_bfloat16 As[128 * 32];
  __shared__ __hip_bfloat16 Bs[128 * 32];
  const int bz = blockIdx.z;
  A += (long)bz * sAb;
  B += (long)bz * sBb;
  const int n0 = blockIdx.x * 128;
  const int m0 = blockIdx.y * 128;
  const int t = threadIdx.x;
  const int lane = t & 63;
  const int w = t >> 6;
  const int wr = w >> 1, wc = w & 1;

  // staging: linear halfword idx within tile; round r covers rows r*64..r*64+63
  const int idx0 = w * 512 + lane * 8;
  const int row0 = idx0 >> 5, col0 = idx0 & 31;

  const __hip_bfloat16* gA0 = A + (long)(m0 + row0) * lda + col0;
  const __hip_bfloat16* gA1 = A + (long)(m0 + row0 + 64) * lda + col0;
  const __hip_bfloat16* gB0 = B + (long)(n0 + row0) * ldb + col0;
  const __hip_bfloat16* gB1 = B + (long)(n0 + row0 + 64) * ldb + col0;
  __hip_bfloat16* lA0 = As + idx0;
  __hip_bfloat16* lA1 = As + idx0 + 2048;
  __hip_bfloat16* lB0 = Bs + idx0;
  __hip_bfloat16* lB1 = Bs + idx0 + 2048;

  f32x4 acc[4][4] = {};

  const int lr = lane & 15;
  const int lk = (lane >> 4) * 8;
  const int kSteps = K >> 5;
  for (int kt = 0; kt < kSteps; ++kt) {
    async_cp16(gA0, lA0); async_cp16(gA1, lA1);
    async_cp16(gB0, lB0); async_cp16(gB1, lB1);
    gA0 += 32; gA1 += 32; gB0 += 32; gB1 += 32;
    __syncthreads();   // compiler drains vmcnt(0) before barrier -> LDS ready
    bf16x8 af[4], bq[4];
    #pragma unroll
    for (int i = 0; i < 4; ++i)
      af[i] = *(const bf16x8*)(As + (wr * 64 + i * 16 + lr) * 32 + lk);
    #pragma unroll
    for (int j = 0; j < 4; ++j)
      bq[j] = *(const bf16x8*)(Bs + (wc * 64 + j * 16 + lr) * 32 + lk);
    #pragma unroll
    for (int i = 0; i < 4; ++i) {
      #pragma unroll
      for (int j = 0; j < 4; ++j)
        acc[i][j] = __builtin_amdgcn_mfma_f32_16x16x32_bf16(af[i], bq[j], acc[i][j], 0, 0, 0);
    }
    __syncthreads();   // protect LDS from next iteration's staging
  }

  // epilogue: C/D mapping col=lane&15, row=(lane>>4)*4+reg  [verified m89/m91]
  const int rbase = m0 + wr * 64 + (lane >> 4) * 4;
  const int cbase = n0 + wc * 64 + lr;
  if (MODE == 0) {
    float* C = (float*)Cv + (long)bz * sCb;
    #pragma unroll
    for (int i = 0; i < 4; ++i)
      #pragma unroll
      for (int j = 0; j < 4; ++j)
        #pragma unroll
        for (int r = 0; r < 4; ++r)
          C[(long)(rbase + i * 16 + r) * ldc + cbase + j * 16] = acc[i][j][r];
  } else if (MODE == 1) {
    __hip_bfloat16* C = (__hip_bfloat16*)Cv + (long)bz * sCb;
    #pragma unroll
    for (int i = 0; i < 4; ++i)
      #pragma unroll
      for (int j = 0; j < 4; ++j)
        #pragma unroll
        for (int r = 0; r < 4; ++r)
          C[(long)(rbase + i * 16 + r) * ldc + cbase + j * 16] = __float2bfloat16(acc[i][j][r]);
  } else {
    float* C = (float*)Cv + (long)bz * sCb;
    const int* Mk = Mask + (long)bz * sMb;
    #pragma unroll
    for (int i = 0; i < 4; ++i)
      #pragma unroll
      for (int j = 0; j < 4; ++j)
        #pragma unroll
        for (int r = 0; r < 4; ++r) {
          const long o = (long)(rbase + i * 16 + r) * ldc + cbase + j * 16;
          const float v = acc[i][j][r] * scale;
          C[o] = (Mk[o] != 0) ? v : -1e20f;   // mask shares layout/stride with S
        }
  }
}

// ---------------- row softmax, fp32 in -> bf16 out IN PLACE ----------------
// one block per row of 2048; reads row as fp32, writes bf16 into the same row base
// (bf16 row occupies the first half of the fp32 row; consumer uses lda=4096)
__global__ __launch_bounds__(256) void softmax_rows(float* __restrict__ S) {
  const long row = blockIdx.x;
  float* srow = S + row * 2048;
  const int t = threadIdx.x;
  const float4 v0 = *(const float4*)(srow + t * 8);
  const float4 v1 = *(const float4*)(srow + t * 8 + 4);
  float f[8] = {v0.x, v0.y, v0.z, v0.w, v1.x, v1.y, v1.z, v1.w};

  float mx = f[0];
  #pragma unroll
  for (int i = 1; i < 8; ++i) mx = fmaxf(mx, f[i]);
  #pragma unroll
  for (int off = 32; off > 0; off >>= 1) mx = fmaxf(mx, __shfl_xor(mx, off));
  __shared__ float redm[4], reds[4];
  if ((t & 63) == 0) redm[t >> 6] = mx;
  __syncthreads();           // all reads of srow complete before this point
  mx = fmaxf(fmaxf(redm[0], redm[1]), fmaxf(redm[2], redm[3]));

  float e[8];
  float s = 0.f;
  #pragma unroll
  for (int i = 0; i < 8; ++i) { e[i] = __expf(f[i] - mx); s += e[i]; }
  #pragma unroll
  for (int off = 32; off > 0; off >>= 1) s += __shfl_xor(s, off);
  if ((t & 63) == 0) reds[t >> 6] = s;
  __syncthreads();
  s = reds[0] + reds[1] + reds[2] + reds[3];
  const float inv = 1.f / s;

  __hip_bfloat16* prow = (__hip_bfloat16*)srow;
  s16x8 o;
  #pragma unroll
  for (int i = 0; i < 8; ++i) o[i] = (short)f2bf_bits(e[i] * inv);
  *(s16x8*)(prow + t * 8) = o;   // in-row overwrite: safe, all reads were pre-barrier
}

extern "C" void kernel_launch(void* const* d_in, const int* in_sizes, int n_in,
                              void* d_out, int out_size, void* d_ws, size_t ws_size,
                              hipStream_t stream) {
  const float* x   = (const float*)d_in[0];
  const int*   msk = (const int*)d_in[1];
  const float* Wqk = (const float*)d_in[2];
  const float* Wvc = (const float*)d_in[3];
  float* out = (float*)d_out;
  char* ws = (char*)d_ws;

  const long NB = 4, n = 2048, d = 1024;

  // workspace layout (bytes): x_bf16 | q_bf16 | vT_bf16 | Wqk_bf16 | Wvc_bf16 | S_fp32
  __hip_bfloat16* xb   = (__hip_bfloat16*)(ws + 0);          // 16 MiB
  __hip_bfloat16* qb   = (__hip_bfloat16*)(ws + 16777216);   // 16 MiB
  __hip_bfloat16* vT   = (__hip_bfloat16*)(ws + 33554432);   // 16 MiB
  __hip_bfloat16* wqkb = (__hip_bfloat16*)(ws + 50331648);   // 2 MiB
  __hip_bfloat16* wvcb = (__hip_bfloat16*)(ws + 52428800);   // 2 MiB
  float*          S    = (float*)(ws + 54525952);            // 64 MiB

  // converts
  cvt_f32_to_bf16<<<8192, 256, 0, stream>>>(x,   xb);
  cvt_f32_to_bf16<<<1024, 256, 0, stream>>>(Wqk, wqkb);
  cvt_f32_to_bf16<<<1024, 256, 0, stream>>>(Wvc, wvcb);

  // q = x @ Wqk^T   [8192 x 1024], K=1024, bf16 out
  gemm_nt<1><<<dim3(8, 64, 1), 256, 0, stream>>>(
      xb, wqkb, qb, nullptr, (int)d, (int)d, (int)d, (int)d, 1.f, 0, 0, 0, 0);

  // vT[b] = Wvc @ x[b]^T   [1024 x 2048] per batch, K=1024, bf16 out
  gemm_nt<1><<<dim3(16, 8, 4), 256, 0, stream>>>(
      wvcb, xb, vT, nullptr, (int)d, (int)d, (int)n, (int)d, 1.f,
      0, n * d, d * n, 0);

  // S[b] = (q[b] @ x[b]^T) / 32, masked -> -1e20, fp32 out
  gemm_nt<2><<<dim3(16, 16, 4), 256, 0, stream>>>(
      qb, xb, S, msk, (int)d, (int)d, (int)n, (int)d, 0.03125f,
      n * d, n * d, n * n, n * n);

  // row softmax in place: fp32 row -> bf16 row (stride 4096 bf16)
  softmax_rows<<<8192, 256, 0, stream>>>(S);

  // out[b] = P[b] @ vT[b]^T   [2048 x 1024], K=2048, fp32 out to d_out
  gemm_nt<0><<<dim3(8, 16, 4), 256, 0, stream>>>(
      (const __hip_bfloat16*)S, vT, out, nullptr, (int)(2 * n), (int)n, (int)d, (int)n, 1.f,
      n * 2 * n, d * n, n * d, 0);
}

// Round 2
// 167.781 us; speedup vs baseline: 1.2590x; 1.2590x over previous
//
#include <hip/hip_runtime.h>
#include <hip/hip_bf16.h>

typedef short bf16x8 __attribute__((ext_vector_type(8)));
typedef short s16x4  __attribute__((ext_vector_type(4)));
typedef short s16x8  __attribute__((ext_vector_type(8)));
typedef float f32x4  __attribute__((ext_vector_type(4)));

static __device__ __forceinline__ void async_cp16(const void* g, void* l) {
  __builtin_amdgcn_global_load_lds(
      (const __attribute__((address_space(1))) unsigned int*)g,
      (__attribute__((address_space(3))) unsigned int*)l, 16, 0, 0);
}

static __device__ __forceinline__ unsigned short f2bf_bits(float f) {
  union { __hip_bfloat16 b; unsigned short u; } cv;
  cv.b = __float2bfloat16(f);
  return cv.u;
}

#define BAR() __builtin_amdgcn_s_barrier()
#define LGKM0() do { asm volatile("s_waitcnt lgkmcnt(0)" ::: "memory"); __builtin_amdgcn_sched_barrier(0); } while (0)
#define VMW(n) do { asm volatile("s_waitcnt vmcnt(" #n ")" ::: "memory"); __builtin_amdgcn_sched_barrier(0); } while (0)

// ---------------- fp32 -> bf16 convert ----------------
__global__ __launch_bounds__(256) void cvt_f32_to_bf16(const float* __restrict__ in,
                                                       __hip_bfloat16* __restrict__ out) {
  const long i = ((long)blockIdx.x * 256 + threadIdx.x) * 4;
  const float4 v = *(const float4*)(in + i);
  s16x4 o;
  o[0] = (short)f2bf_bits(v.x);
  o[1] = (short)f2bf_bits(v.y);
  o[2] = (short)f2bf_bits(v.z);
  o[3] = (short)f2bf_bits(v.w);
  *(s16x4*)(out + i) = o;
}

// ---------------- 256x256 8-phase NT GEMM ----------------
// C[m,n] = sum_k A[m,k]*B[n,k].  BM=BN=256, BK=64, 512 threads = 8 waves (2M x 4N).
// Per wave: 128x64 output = acc[8][4] of 16x16 frags; 64 MFMA per K-tile, split into
// 4 phases of 16 (quadrant = (m-half mh, k-sub ks)).  LDS 128 KiB:
//   buf b (b=K-tile&1) at b*65536:
//     A half h (rows {wm*128 + h*64 + 0..63}) at +h*16384 : [pr:128][kbyte:128], swz bits4-6 ^= pr&7
//     B khalf ks at +32768+ks*16384 : [pc:256][kbyte:64],  swz bits4-5 ^= (pc>>1)&3
// Stage schedule (iteration j computes tiles t0=2j (buf0, P1-P4), t1=2j+1 (buf1, P5-P8));
// one half-tile (2 x global_load_lds per thread) staged per phase:
//   P1: A1(t1)  P2: Bk1(t1)  P3: Bk0(t0+2)  P4: A0(t0+2)  [VMW(4)]
//   P5: A1(t0+2) P6: Bk1(t0+2) P7: Bk0(t1+2) P8: A0(t1+2) [VMW(4)]
// Every stage targets a region whose last ds_read was in a strictly earlier phase
// (safe: reads complete before each phase's trailing barrier); vmcnt(4) leaves exactly
// the 2 newest half-tiles in flight and guarantees the next 4 phases' data has landed.
struct GemmDesc {
  const __hip_bfloat16* A; const __hip_bfloat16* B; void* C;
  int lda, ldb, ldc, mT, nT, tpb; long sA, sB, sC;
};

#define STAGE_A(bb, h, kt) do { \
  const __hip_bfloat16* sA0_ = Ab + aOff0 + (long)(h) * 64 * g.lda + (kt) * 64; \
  const __hip_bfloat16* sA1_ = Ab + aOff1 + (long)(h) * 64 * g.lda + (kt) * 64; \
  char* dA_ = lds + (bb) * 65536 + (h) * 16384 + t * 16; \
  async_cp16(sA0_, dA_); async_cp16(sA1_, dA_ + 8192); } while (0)

#define STAGE_B(bb, ks, kt) do { \
  const __hip_bfloat16* sB0_ = Bb + bOff0 + (kt) * 64 + (ks) * 32; \
  const __hip_bfloat16* sB1_ = Bb + bOff1 + (kt) * 64 + (ks) * 32; \
  char* dB_ = lds + (bb) * 65536 + 32768 + (ks) * 16384 + t * 16; \
  async_cp16(sB0_, dB_); async_cp16(sB1_, dB_ + 8192); } while (0)

// phase: ds-reads, stage (VA_ARGS), barrier, lgkm0, MFMA cluster, optional vm wait, barrier
#define PHASE(bb, mh, ks, READB, VM_STMT, ...) do { \
  if (READB) { \
    _Pragma("unroll") \
    for (int nf = 0; nf < 4; ++nf) \
      bq[nf] = *(const bf16x8*)(lds + (bb) * 65536 + 32768 + (ks) * 16384 + \
                (wn * 64 + nf * 16 + (lane & 15)) * 64 + (((lane >> 4) * 16) ^ bXor)); \
  } \
  _Pragma("unroll") \
  for (int mm = 0; mm < 4; ++mm) \
    af[mm] = *(const bf16x8*)(lds + (bb) * 65536 + (mh) * 16384 + \
              (wm * 64 + mm * 16 + (lane & 15)) * 128 + (((ks) * 64 + (lane >> 4) * 16) ^ aXor)); \
  __VA_ARGS__; \
  BAR(); \
  LGKM0(); \
  __builtin_amdgcn_s_setprio(1); \
  _Pragma("unroll") \
  for (int mm = 0; mm < 4; ++mm) \
    _Pragma("unroll") \
    for (int nf = 0; nf < 4; ++nf) \
      acc[(mh) * 4 + mm][nf] = \
        __builtin_amdgcn_mfma_f32_16x16x32_bf16(af[mm], bq[nf], acc[(mh) * 4 + mm][nf], 0, 0, 0); \
  __builtin_amdgcn_s_setprio(0); \
  VM_STMT; \
  BAR(); } while (0)

template<int MODE>  // 0: fp32 store, 1: bf16 store
__global__ __launch_bounds__(512, 2) void gemm8(GemmDesc g0, GemmDesc g1, int nb0, int K) {
  __shared__ char lds[131072];
  const int bid = blockIdx.x, nwg = gridDim.x;
  // XCD-aware bijective swizzle (all grids are multiples of 8)
  const int wg = (bid & 7) * (nwg >> 3) + (bid >> 3);
  GemmDesc g = (wg < nb0) ? g0 : g1;
  const int id = (wg < nb0) ? wg : wg - nb0;
  const int bz = id / g.tpb;
  const int tl = id - bz * g.tpb;
  const int bm = tl / g.nT;
  const int bn = tl - bm * g.nT;
  const long m0 = (long)bm * 256, n0 = (long)bn * 256;
  const __hip_bfloat16* Ab = g.A + bz * g.sA;
  const __hip_bfloat16* Bb = g.B + bz * g.sB;
  const int t = threadIdx.x;
  const int lane = t & 63, w = t >> 6;
  const int wm = w >> 2, wn = w & 3;

  // staging source precompute. A: thread t covers dest L=q*8192+t*16 -> pr=q*64+(t>>3),
  // dest slot t&7; its source slot = (t&7) ^ (pr&7)  (XOR involution: linear dest +
  // inverse-swizzled source == swizzled read).
  const int aR = t >> 3;
  const int aSlot = (t & 7) ^ (aR & 7);
  const long aOff0 = (m0 + aR) * (long)g.lda + aSlot * 8;
  const long aOff1 = (m0 + 128 + aR) * (long)g.lda + aSlot * 8;
  // B: dest L -> pc=q*128+(t>>2), dest slot t&3; source slot = (t&3) ^ ((pc>>1)&3)
  const int bR = t >> 2;
  const int bSlot = (t & 3) ^ ((t >> 3) & 3);
  const long bOff0 = (n0 + bR) * (long)g.ldb + bSlot * 8;
  const long bOff1 = (n0 + 128 + bR) * (long)g.ldb + bSlot * 8;
  // read-side swizzle constants
  const int aXor = (lane & 7) << 4;          // == (pr&7)<<4 for pr = ..16s.. + (lane&15)
  const int bXor = ((lane >> 1) & 3) << 4;   // == ((pc>>1)&3)<<4 for pc = ..16s.. + (lane&15)

  f32x4 acc[8][4] = {};
  bf16x8 af[4], bq[4];

  const int nt = K >> 6;   // K-tiles of 64
  const int nJ = nt >> 1;  // iterations (2 K-tiles each)

  // prologue: tile0 fully + tile1 {A0, Bk0}; leave 2 half-tiles in flight
  STAGE_A(0, 0, 0); STAGE_A(0, 1, 0); STAGE_B(0, 0, 0); STAGE_B(0, 1, 0);
  STAGE_A(1, 0, 1); STAGE_B(1, 0, 1);
  VMW(4);
  BAR();

  for (int j = 0; j < nJ; ++j) {
    const int t0 = 2 * j, t1 = 2 * j + 1;
    const bool full = (j + 1 < nJ);
    PHASE(0, 0, 0, true,  {},                                    STAGE_A(1, 1, t1));
    PHASE(0, 1, 0, false, {},                                    STAGE_B(1, 1, t1));
    PHASE(0, 0, 1, true,  {},                                    if (full) STAGE_B(0, 0, t0 + 2));
    PHASE(0, 1, 1, false, { if (full) { VMW(4); } else { VMW(0); } },
                                                                 if (full) STAGE_A(0, 0, t0 + 2));
    PHASE(1, 0, 0, true,  {},                                    if (full) STAGE_A(0, 1, t0 + 2));
    PHASE(1, 1, 0, false, {},                                    if (full) STAGE_B(0, 1, t0 + 2));
    PHASE(1, 0, 1, true,  {},                                    if (full) STAGE_B(1, 0, t1 + 2));
    PHASE(1, 1, 1, false, { if (full) { VMW(4); } },             if (full) STAGE_A(1, 0, t1 + 2));
  }

  // epilogue: C/D mapping col=lane&15, row=(lane>>4)*4+reg
  const long crow0 = m0 + wm * 128 + ((lane >> 4) * 4);
  const long ccol0 = n0 + wn * 64 + (lane & 15);
  if (MODE == 0) {
    float* C = (float*)g.C + bz * g.sC;
    #pragma unroll
    for (int m = 0; m < 8; ++m)
      #pragma unroll
      for (int nf = 0; nf < 4; ++nf)
        #pragma unroll
        for (int r = 0; r < 4; ++r)
          C[(crow0 + m * 16 + r) * g.ldc + ccol0 + nf * 16] = acc[m][nf][r];
  } else {
    __hip_bfloat16* C = (__hip_bfloat16*)g.C + bz * g.sC;
    #pragma unroll
    for (int m = 0; m < 8; ++m)
      #pragma unroll
      for (int nf = 0; nf < 4; ++nf)
        #pragma unroll
        for (int r = 0; r < 4; ++r)
          C[(crow0 + m * 16 + r) * g.ldc + ccol0 + nf * 16] = __float2bfloat16(acc[m][nf][r]);
  }
}

// ---------------- row softmax with mask+scale, fp32 in -> bf16 out IN PLACE ----------------
// f = mask ? s/32 : -1e20 ; all-masked rows degrade to the uniform softmax like the reference.
__global__ __launch_bounds__(256) void softmax_rows(float* __restrict__ S,
                                                    const int* __restrict__ Mask) {
  const long row = blockIdx.x;
  float* srow = S + row * 2048;
  const int* mrow = Mask + row * 2048;
  const int t = threadIdx.x;
  const float4 v0 = *(const float4*)(srow + t * 8);
  const float4 v1 = *(const float4*)(srow + t * 8 + 4);
  const int4 q0 = *(const int4*)(mrow + t * 8);
  const int4 q1 = *(const int4*)(mrow + t * 8 + 4);
  float f[8];
  f[0] = q0.x ? v0.x * 0.03125f : -1e20f;
  f[1] = q0.y ? v0.y * 0.03125f : -1e20f;
  f[2] = q0.z ? v0.z * 0.03125f : -1e20f;
  f[3] = q0.w ? v0.w * 0.03125f : -1e20f;
  f[4] = q1.x ? v1.x * 0.03125f : -1e20f;
  f[5] = q1.y ? v1.y * 0.03125f : -1e20f;
  f[6] = q1.z ? v1.z * 0.03125f : -1e20f;
  f[7] = q1.w ? v1.w * 0.03125f : -1e20f;

  float mx = f[0];
  #pragma unroll
  for (int i = 1; i < 8; ++i) mx = fmaxf(mx, f[i]);
  #pragma unroll
  for (int off = 32; off > 0; off >>= 1) mx = fmaxf(mx, __shfl_xor(mx, off));
  __shared__ float redm[4], reds[4];
  if ((t & 63) == 0) redm[t >> 6] = mx;
  __syncthreads();   // also orders all srow reads before the in-place write below
  mx = fmaxf(fmaxf(redm[0], redm[1]), fmaxf(redm[2], redm[3]));

  float e[8];
  float s = 0.f;
  #pragma unroll
  for (int i = 0; i < 8; ++i) { e[i] = __expf(f[i] - mx); s += e[i]; }
  #pragma unroll
  for (int off = 32; off > 0; off >>= 1) s += __shfl_xor(s, off);
  if ((t & 63) == 0) reds[t >> 6] = s;
  __syncthreads();
  s = reds[0] + reds[1] + reds[2] + reds[3];
  const float inv = 1.f / s;

  __hip_bfloat16* prow = (__hip_bfloat16*)srow;
  s16x8 o;
  #pragma unroll
  for (int i = 0; i < 8; ++i) o[i] = (short)f2bf_bits(e[i] * inv);
  *(s16x8*)(prow + t * 8) = o;
}

extern "C" void kernel_launch(void* const* d_in, const int* in_sizes, int n_in,
                              void* d_out, int out_size, void* d_ws, size_t ws_size,
                              hipStream_t stream) {
  const float* x   = (const float*)d_in[0];
  const int*   msk = (const int*)d_in[1];
  const float* Wqk = (const float*)d_in[2];
  const float* Wvc = (const float*)d_in[3];
  float* out = (float*)d_out;
  char* ws = (char*)d_ws;

  // workspace layout: x_bf16 | q_bf16 | vT_bf16 | Wqk_bf16 | Wvc_bf16 | S_fp32
  __hip_bfloat16* xb   = (__hip_bfloat16*)(ws + 0);          // 16 MiB
  __hip_bfloat16* qb   = (__hip_bfloat16*)(ws + 16777216);   // 16 MiB
  __hip_bfloat16* vT   = (__hip_bfloat16*)(ws + 33554432);   // 16 MiB
  __hip_bfloat16* wqkb = (__hip_bfloat16*)(ws + 50331648);   // 2 MiB
  __hip_bfloat16* wvcb = (__hip_bfloat16*)(ws + 52428800);   // 2 MiB
  float*          S    = (float*)(ws + 54525952);            // 64 MiB

  cvt_f32_to_bf16<<<8192, 256, 0, stream>>>(x,   xb);
  cvt_f32_to_bf16<<<1024, 256, 0, stream>>>(Wqk, wqkb);
  cvt_f32_to_bf16<<<1024, 256, 0, stream>>>(Wvc, wvcb);

  // grouped dispatch: q = x @ Wqk^T (8192x1024, 128 tiles) + vT[b] = Wvc @ x[b]^T (128 tiles)
  GemmDesc gq{xb,   wqkb, qb, 1024, 1024, 1024, 32, 4, 128, 0L, 0L, 0L};
  GemmDesc gv{wvcb, xb,   vT, 1024, 1024, 2048,  4, 8,  32, 0L, 2097152L, 2097152L};
  gemm8<1><<<dim3(256), 512, 0, stream>>>(gq, gv, 128, 1024);

  // S[b] = q[b] @ x[b]^T  (fp32, raw scores; scale+mask applied in softmax)
  GemmDesc gs{qb, xb, S, 1024, 1024, 2048, 8, 8, 64, 2097152L, 2097152L, 4194304L};
  gemm8<0><<<dim3(256), 512, 0, stream>>>(gs, gs, 256, 1024);

  // softmax rows: fp32+mask -> bf16 in place (P row stride 4096 halfwords)
  softmax_rows<<<dim3(8192), 256, 0, stream>>>(S, msk);

  // out[b] = P[b] @ vT[b]^T  (K=2048, fp32 out)
  GemmDesc go{(const __hip_bfloat16*)S, vT, out, 4096, 2048, 1024, 8, 4, 32,
              8388608L, 2097152L, 2097152L};
  gemm8<0><<<dim3(128), 512, 0, stream>>>(go, go, 128, 2048);
}

// Round 3
// 144.453 us; speedup vs baseline: 1.4624x; 1.1615x over previous
//
#include <hip/hip_runtime.h>
#include <hip/hip_bf16.h>

typedef short bf16x8 __attribute__((ext_vector_type(8)));
typedef short s16x4  __attribute__((ext_vector_type(4)));
typedef short s16x8  __attribute__((ext_vector_type(8)));
typedef float f32x4  __attribute__((ext_vector_type(4)));

static __device__ __forceinline__ void async_cp16(const void* g, void* l) {
  __builtin_amdgcn_global_load_lds(
      (const __attribute__((address_space(1))) unsigned int*)g,
      (__attribute__((address_space(3))) unsigned int*)l, 16, 0, 0);
}

static __device__ __forceinline__ unsigned short f2bf_bits(float f) {
  union { __hip_bfloat16 b; unsigned short u; } cv;
  cv.b = __float2bfloat16(f);
  return cv.u;
}
static __device__ __forceinline__ float bf2f(short u) {
  union { float f; unsigned v; } cv;
  cv.v = ((unsigned)(unsigned short)u) << 16;
  return cv.f;
}

#define BAR() __builtin_amdgcn_s_barrier()
#define LGKM0() do { asm volatile("s_waitcnt lgkmcnt(0)" ::: "memory"); __builtin_amdgcn_sched_barrier(0); } while (0)
#define VMW(n) do { asm volatile("s_waitcnt vmcnt(" #n ")" ::: "memory"); __builtin_amdgcn_sched_barrier(0); } while (0)

// ---------------- fp32 -> bf16 convert ----------------
__global__ __launch_bounds__(256) void cvt_f32_to_bf16(const float* __restrict__ in,
                                                       __hip_bfloat16* __restrict__ out) {
  const long i = ((long)blockIdx.x * 256 + threadIdx.x) * 4;
  const float4 v = *(const float4*)(in + i);
  s16x4 o;
  o[0] = (short)f2bf_bits(v.x);
  o[1] = (short)f2bf_bits(v.y);
  o[2] = (short)f2bf_bits(v.z);
  o[3] = (short)f2bf_bits(v.w);
  *(s16x4*)(out + i) = o;
}

// ---------------- 16-wave tri-buffered NT GEMM ----------------
// C[m,n] = sum_k A[m,k]*B[n,k].  1024 threads = 16 waves (4x4).  BN=256 always.
// cfg1 (qv,S): BM=256, BK=32 -> per-wave 64x64, acc[4][4], LDS 3x32KB.
// cfg2 (out):  BM=128, BK=64 -> per-wave 32x64, acc[2][4], LDS 3x48KB.
// Phase = one K-tile: [ds_reads(buf t%3) | stage tile t+2 -> buf (t+2)%3 |
//   lgkmcnt(0) | 16 MFMA | vmcnt(KW) | barrier].  One barrier/phase: reads of
// tile t complete at lgkmcnt(0) BEFORE the closing barrier, so phase t+1's
// stages (targeting buf t%3) can never race them.  vmcnt(KW) leaves exactly
// tile t+2's KW loads in flight => tile t+1 landed (2-phase prefetch depth).
// LDS swizzle (bank-conflict): row r of W bytes, 16B slot s stored at
// s ^ swz(r), swz = (W==64) ? (r>>1)&3 : r&7; staged by inverse-permuting the
// GLOBAL source slot (involution) so global_load_lds dest stays linear.
struct GemmDesc {
  const __hip_bfloat16* A; const __hip_bfloat16* B; void* C;
  int lda, ldb, ldc, nT, tpb; long sA, sB, sC; float cscale;
};

template<int MODE, int BM_, int BK_>   // MODE 0: fp32 store, 1: bf16 store (x cscale)
__global__ __launch_bounds__(1024, 4) void gemm16(GemmDesc g0, GemmDesc g1, int nb0, int K) {
  constexpr int MR = BM_ / 64;          // m-frags per wave
  constexpr int KR = BK_ / 32;          // k-subtiles
  constexpr int W  = BK_ * 2;           // LDS row bytes
  constexpr int NB = (256 * W) / 16384; // B 16KB chunks
  constexpr int BUFSZ = 16384 + NB * 16384;
  constexpr int KW = 1 + NB;            // stage ops (cp16/thread) per tile
  __shared__ char lds[3 * BUFSZ];

  const int bid = blockIdx.x, nwg = gridDim.x;
  const int wg = (bid & 7) * (nwg >> 3) + (bid >> 3);   // XCD swizzle (nwg%8==0)
  GemmDesc g = (wg < nb0) ? g0 : g1;
  const int id = (wg < nb0) ? wg : wg - nb0;
  const int bz = id / g.tpb, tl = id - bz * g.tpb;
  const int bm = tl / g.nT, bn = tl - bm * g.nT;
  const long m0 = (long)bm * BM_, n0 = (long)bn * 256;
  const __hip_bfloat16* Ab = g.A + bz * g.sA;
  const __hip_bfloat16* Bb = g.B + bz * g.sB;

  const int t = threadIdx.x;
  const int lane = t & 63, w = t >> 6;
  const int wm = w >> 2, wn = w & 3;
  const int lr = lane & 15, cs = lane >> 4;

  // ---- staging source pointers (inverse-swizzled global slot) ----
  const int rA  = t / (W / 16);               // region row this thread fills
  const int dsl = t % (W / 16);               // linear dest slot
  const int ssl = dsl ^ ((W == 64) ? ((rA >> 1) & 3) : (rA & 7));
  const __hip_bfloat16* aSt  = Ab + (m0 + rA) * g.lda + ssl * 8;
  const __hip_bfloat16* bSt0 = Bb + (n0 + rA) * g.ldb + ssl * 8;
  const __hip_bfloat16* bSt1 = Bb + (n0 + 128 + rA) * g.ldb + ssl * 8; // NB==2 only

  // ---- read-side swizzled LDS byte offsets ----
  const int axor = (W == 64) ? (((lr >> 1) & 3) << 4) : ((lr & 7) << 4);
  int aRd[MR][KR], bRd[4][KR];
  #pragma unroll
  for (int mm = 0; mm < MR; ++mm)
    #pragma unroll
    for (int ks = 0; ks < KR; ++ks)
      aRd[mm][ks] = (wm * (BM_ / 4) + mm * 16 + lr) * W + ((((ks * 4 + cs) << 4) ^ axor));
  #pragma unroll
  for (int nf = 0; nf < 4; ++nf)
    #pragma unroll
    for (int ks = 0; ks < KR; ++ks)
      bRd[nf][ks] = 16384 + (wn * 64 + nf * 16 + lr) * W + ((((ks * 4 + cs) << 4) ^ axor));

  f32x4 acc[MR][4] = {};

  #define STAGE(kt, base) do { \
    async_cp16(aSt + (long)(kt) * BK_, lds + (base) + t * 16); \
    async_cp16(bSt0 + (long)(kt) * BK_, lds + (base) + 16384 + t * 16); \
    if (NB == 2) async_cp16(bSt1 + (long)(kt) * BK_, lds + (base) + 32768 + t * 16); \
  } while (0)
  #define VM_KW() do { if constexpr (KW == 2) { VMW(2); } else { VMW(3); } } while (0)

  const int nt = K / BK_;
  // prologue: tiles 0,1 staged; wait tile0 (leave tile1's KW in flight)
  STAGE(0, 0);
  STAGE(1, BUFSZ);
  VM_KW();
  BAR();

  int rb = 0, sb = 2 * BUFSZ;
  for (int tt = 0; tt < nt; ++tt) {
    bf16x8 af[MR][KR], bq[4][KR];
    #pragma unroll
    for (int mm = 0; mm < MR; ++mm)
      #pragma unroll
      for (int ks = 0; ks < KR; ++ks)
        af[mm][ks] = *(const bf16x8*)(lds + rb + aRd[mm][ks]);
    #pragma unroll
    for (int nf = 0; nf < 4; ++nf)
      #pragma unroll
      for (int ks = 0; ks < KR; ++ks)
        bq[nf][ks] = *(const bf16x8*)(lds + rb + bRd[nf][ks]);
    if (tt + 2 < nt) STAGE(tt + 2, sb);
    LGKM0();
    __builtin_amdgcn_s_setprio(1);
    #pragma unroll
    for (int ks = 0; ks < KR; ++ks)
      #pragma unroll
      for (int mm = 0; mm < MR; ++mm)
        #pragma unroll
        for (int nf = 0; nf < 4; ++nf)
          acc[mm][nf] = __builtin_amdgcn_mfma_f32_16x16x32_bf16(af[mm][ks], bq[nf][ks], acc[mm][nf], 0, 0, 0);
    __builtin_amdgcn_s_setprio(0);
    if (tt + 2 < nt) { VM_KW(); } else { VMW(0); }
    BAR();
    rb = (rb == 2 * BUFSZ) ? 0 : rb + BUFSZ;
    sb = (sb == 2 * BUFSZ) ? 0 : sb + BUFSZ;
  }
  #undef STAGE
  #undef VM_KW

  // epilogue: C/D mapping col=lane&15, row=(lane>>4)*4+reg  [verified m89/m91]
  const long crow0 = m0 + wm * (BM_ / 4) + cs * 4;
  const long ccol0 = n0 + wn * 64 + lr;
  if (MODE == 0) {
    float* C = (float*)g.C + bz * g.sC;
    #pragma unroll
    for (int mm = 0; mm < MR; ++mm)
      #pragma unroll
      for (int nf = 0; nf < 4; ++nf)
        #pragma unroll
        for (int rr = 0; rr < 4; ++rr)
          C[(crow0 + mm * 16 + rr) * g.ldc + ccol0 + nf * 16] = acc[mm][nf][rr];
  } else {
    __hip_bfloat16* C = (__hip_bfloat16*)g.C + bz * g.sC;
    #pragma unroll
    for (int mm = 0; mm < MR; ++mm)
      #pragma unroll
      for (int nf = 0; nf < 4; ++nf)
        #pragma unroll
        for (int rr = 0; rr < 4; ++rr)
          C[(crow0 + mm * 16 + rr) * g.ldc + ccol0 + nf * 16] =
              __float2bfloat16(acc[mm][nf][rr] * g.cscale);
  }
}

// ---------------- row softmax: bf16 scores (pre-scaled) + mask -> bf16 P in place ----------------
__global__ __launch_bounds__(256) void softmax_rows(__hip_bfloat16* __restrict__ S,
                                                    const int* __restrict__ Mask) {
  const long row = blockIdx.x;
  short* srow = (short*)(S + row * 2048);
  const int* mrow = Mask + row * 2048;
  const int t = threadIdx.x;
  const s16x8 sv = *(const s16x8*)(srow + t * 8);
  const int4 q0 = *(const int4*)(mrow + t * 8);
  const int4 q1 = *(const int4*)(mrow + t * 8 + 4);
  float f[8];
  f[0] = q0.x ? bf2f(sv[0]) : -1e20f;
  f[1] = q0.y ? bf2f(sv[1]) : -1e20f;
  f[2] = q0.z ? bf2f(sv[2]) : -1e20f;
  f[3] = q0.w ? bf2f(sv[3]) : -1e20f;
  f[4] = q1.x ? bf2f(sv[4]) : -1e20f;
  f[5] = q1.y ? bf2f(sv[5]) : -1e20f;
  f[6] = q1.z ? bf2f(sv[6]) : -1e20f;
  f[7] = q1.w ? bf2f(sv[7]) : -1e20f;

  float mx = f[0];
  #pragma unroll
  for (int i = 1; i < 8; ++i) mx = fmaxf(mx, f[i]);
  #pragma unroll
  for (int off = 32; off > 0; off >>= 1) mx = fmaxf(mx, __shfl_xor(mx, off));
  __shared__ float redm[4], reds[4];
  if ((t & 63) == 0) redm[t >> 6] = mx;
  __syncthreads();   // also orders all srow reads before the in-place write below
  mx = fmaxf(fmaxf(redm[0], redm[1]), fmaxf(redm[2], redm[3]));

  float e[8];
  float s = 0.f;
  #pragma unroll
  for (int i = 0; i < 8; ++i) { e[i] = __expf(f[i] - mx); s += e[i]; }
  #pragma unroll
  for (int off = 32; off > 0; off >>= 1) s += __shfl_xor(s, off);
  if ((t & 63) == 0) reds[t >> 6] = s;
  __syncthreads();
  s = reds[0] + reds[1] + reds[2] + reds[3];
  const float inv = 1.f / s;

  s16x8 o;
  #pragma unroll
  for (int i = 0; i < 8; ++i) o[i] = (short)f2bf_bits(e[i] * inv);
  *(s16x8*)(srow + t * 8) = o;
}

extern "C" void kernel_launch(void* const* d_in, const int* in_sizes, int n_in,
                              void* d_out, int out_size, void* d_ws, size_t ws_size,
                              hipStream_t stream) {
  const float* x   = (const float*)d_in[0];
  const int*   msk = (const int*)d_in[1];
  const float* Wqk = (const float*)d_in[2];
  const float* Wvc = (const float*)d_in[3];
  float* out = (float*)d_out;
  char* ws = (char*)d_ws;

  // workspace: x_bf16 | q_bf16 (pre-scaled by 1/32) | vT_bf16 | Wqk_bf16 | Wvc_bf16 | S_bf16
  __hip_bfloat16* xb   = (__hip_bfloat16*)(ws + 0);          // 16 MiB
  __hip_bfloat16* qb   = (__hip_bfloat16*)(ws + 16777216);   // 16 MiB
  __hip_bfloat16* vT   = (__hip_bfloat16*)(ws + 33554432);   // 16 MiB
  __hip_bfloat16* wqkb = (__hip_bfloat16*)(ws + 50331648);   // 2 MiB
  __hip_bfloat16* wvcb = (__hip_bfloat16*)(ws + 52428800);   // 2 MiB
  __hip_bfloat16* Sbf  = (__hip_bfloat16*)(ws + 54525952);   // 32 MiB

  cvt_f32_to_bf16<<<8192, 256, 0, stream>>>(x,   xb);
  cvt_f32_to_bf16<<<1024, 256, 0, stream>>>(Wqk, wqkb);
  cvt_f32_to_bf16<<<1024, 256, 0, stream>>>(Wvc, wvcb);

  // grouped: q = (x @ Wqk^T)/32  [8192x1024, 128 tiles]  +  vT[b] = Wvc @ x[b]^T [128 tiles]
  GemmDesc gq{xb,   wqkb, qb, 1024, 1024, 1024, 4, 128, 0L, 0L, 0L, 0.03125f};
  GemmDesc gv{wvcb, xb,   vT, 1024, 1024, 2048, 8, 32, 0L, 2097152L, 2097152L, 1.f};
  gemm16<1, 256, 32><<<dim3(256), 1024, 0, stream>>>(gq, gv, 128, 1024);

  // S[b] = q'[b] @ x[b]^T  (bf16 scores, already scaled)
  GemmDesc gs{qb, xb, Sbf, 1024, 1024, 2048, 8, 64, 2097152L, 2097152L, 4194304L, 1.f};
  gemm16<1, 256, 32><<<dim3(256), 1024, 0, stream>>>(gs, gs, 256, 1024);

  // softmax rows: bf16+mask -> bf16 P in place (stride 2048)
  softmax_rows<<<dim3(8192), 256, 0, stream>>>(Sbf, msk);

  // out[b] = P[b] @ vT[b]^T  (K=2048, fp32 out), BM=128/BK=64 variant -> grid 256
  GemmDesc go{Sbf, vT, out, 2048, 2048, 1024, 4, 64, 4194304L, 2097152L, 2097152L, 1.f};
  gemm16<0, 128, 64><<<dim3(256), 1024, 0, stream>>>(go, go, 256, 2048);
}

// Round 4
// 144.304 us; speedup vs baseline: 1.4639x; 1.0010x over previous
//
#include <hip/hip_runtime.h>
#include <hip/hip_bf16.h>

typedef short bf16x8 __attribute__((ext_vector_type(8)));
typedef short s16x4  __attribute__((ext_vector_type(4)));
typedef short s16x8  __attribute__((ext_vector_type(8)));
typedef float f32x4  __attribute__((ext_vector_type(4)));

static __device__ __forceinline__ void async_cp16(const void* g, void* l) {
  __builtin_amdgcn_global_load_lds(
      (const __attribute__((address_space(1))) unsigned int*)g,
      (__attribute__((address_space(3))) unsigned int*)l, 16, 0, 0);
}

static __device__ __forceinline__ unsigned short f2bf_bits(float f) {
  union { __hip_bfloat16 b; unsigned short u; } cv;
  cv.b = __float2bfloat16(f);
  return cv.u;
}
static __device__ __forceinline__ float bf2f(short u) {
  union { float f; unsigned v; } cv;
  cv.v = ((unsigned)(unsigned short)u) << 16;
  return cv.f;
}

#define BAR() __builtin_amdgcn_s_barrier()
#define VMW(n) do { asm volatile("s_waitcnt vmcnt(" #n ")" ::: "memory"); __builtin_amdgcn_sched_barrier(0); } while (0)

// ---------------- fp32 -> bf16 convert ----------------
__global__ __launch_bounds__(256) void cvt_f32_to_bf16(const float* __restrict__ in,
                                                       __hip_bfloat16* __restrict__ out) {
  const long i = ((long)blockIdx.x * 256 + threadIdx.x) * 4;
  const float4 v = *(const float4*)(in + i);
  s16x4 o;
  o[0] = (short)f2bf_bits(v.x);
  o[1] = (short)f2bf_bits(v.y);
  o[2] = (short)f2bf_bits(v.z);
  o[3] = (short)f2bf_bits(v.w);
  *(s16x4*)(out + i) = o;
}

// ---------------- 16-wave tri-buffered NT GEMM ----------------
// C[m,n] = sum_k A[m,k]*B[n,k].  1024 threads = 16 waves (4x4).  BN=256 always.
// cfg1 (qv,S): BM=256, BK=32 -> per-wave 64x64, acc[4][4], LDS 3x32KB.
// cfg2 (out):  BM=128, BK=64 -> per-wave 32x64, acc[2][4], LDS 3x48KB.
// Per K-tile: [ds_reads(buf t%3) | stage tile t+2 -> buf (t+2)%3 | MFMA with
//   COMPILER-INSERTED fine-grained lgkmcnt (no manual drain: the explicit
//   lgkmcnt(0)+sched_barrier serialized the LDS burst against the MFMA burst
//   and capped the kernel at ~880 TF / MfmaUtil 34%) | vmcnt(KW)+sched_barrier
//   | s_barrier].
// Invariants (unchanged from round 3): reads of tile t retire before the MFMA
// cluster's last use, hence before BAR; stage(t+2) targets buf[(t+2)%3] whose
// last readers (tile t-1) finished before the PREVIOUS barrier; vmcnt(KW)
// before BAR guarantees tile t+1 landed in every wave before any wave's
// reads(t+1) — the sched_barrier in VMW also stops the compiler hoisting next
// iteration's ds_reads above the barrier (that would race other waves' still
// in-flight staging).
// LDS swizzle: row r of W bytes, 16B slot s stored at s ^ swz(r),
// swz = (W==64) ? (r>>1)&3 : r&7; staged by inverse-permuting the GLOBAL
// source slot (involution) so the global_load_lds dest stays linear.
struct GemmDesc {
  const __hip_bfloat16* A; const __hip_bfloat16* B; void* C;
  int lda, ldb, ldc, nT, tpb; long sA, sB, sC; float cscale;
};

template<int MODE, int BM_, int BK_>   // MODE 0: fp32 store, 1: bf16 store (x cscale)
__global__ __launch_bounds__(1024, 4) void gemm16(GemmDesc g0, GemmDesc g1, int nb0, int K) {
  constexpr int MR = BM_ / 64;          // m-frags per wave
  constexpr int KR = BK_ / 32;          // k-subtiles
  constexpr int W  = BK_ * 2;           // LDS row bytes
  constexpr int NB = (256 * W) / 16384; // B 16KB chunks
  constexpr int BUFSZ = 16384 + NB * 16384;
  constexpr int KW = 1 + NB;            // stage ops (cp16/thread) per tile
  __shared__ char lds[3 * BUFSZ];

  const int bid = blockIdx.x, nwg = gridDim.x;
  const int wg = (bid & 7) * (nwg >> 3) + (bid >> 3);   // XCD swizzle (nwg%8==0)
  GemmDesc g = (wg < nb0) ? g0 : g1;
  const int id = (wg < nb0) ? wg : wg - nb0;
  const int bz = id / g.tpb, tl = id - bz * g.tpb;
  const int bm = tl / g.nT, bn = tl - bm * g.nT;
  const long m0 = (long)bm * BM_, n0 = (long)bn * 256;
  const __hip_bfloat16* Ab = g.A + bz * g.sA;
  const __hip_bfloat16* Bb = g.B + bz * g.sB;

  const int t = threadIdx.x;
  const int lane = t & 63, w = t >> 6;
  const int wm = w >> 2, wn = w & 3;
  const int lr = lane & 15, cs = lane >> 4;

  // ---- staging source pointers (inverse-swizzled global slot) ----
  const int rA  = t / (W / 16);               // region row this thread fills
  const int dsl = t % (W / 16);               // linear dest slot
  const int ssl = dsl ^ ((W == 64) ? ((rA >> 1) & 3) : (rA & 7));
  const __hip_bfloat16* aSt  = Ab + (m0 + rA) * g.lda + ssl * 8;
  const __hip_bfloat16* bSt0 = Bb + (n0 + rA) * g.ldb + ssl * 8;
  const __hip_bfloat16* bSt1 = Bb + (n0 + 128 + rA) * g.ldb + ssl * 8; // NB==2 only

  // ---- read-side swizzled LDS byte offsets ----
  const int axor = (W == 64) ? (((lr >> 1) & 3) << 4) : ((lr & 7) << 4);
  int aRd[MR][KR], bRd[4][KR];
  #pragma unroll
  for (int mm = 0; mm < MR; ++mm)
    #pragma unroll
    for (int ks = 0; ks < KR; ++ks)
      aRd[mm][ks] = (wm * (BM_ / 4) + mm * 16 + lr) * W + ((((ks * 4 + cs) << 4) ^ axor));
  #pragma unroll
  for (int nf = 0; nf < 4; ++nf)
    #pragma unroll
    for (int ks = 0; ks < KR; ++ks)
      bRd[nf][ks] = 16384 + (wn * 64 + nf * 16 + lr) * W + ((((ks * 4 + cs) << 4) ^ axor));

  f32x4 acc[MR][4] = {};

  #define STAGE(kt, base) do { \
    async_cp16(aSt + (long)(kt) * BK_, lds + (base) + t * 16); \
    async_cp16(bSt0 + (long)(kt) * BK_, lds + (base) + 16384 + t * 16); \
    if (NB == 2) async_cp16(bSt1 + (long)(kt) * BK_, lds + (base) + 32768 + t * 16); \
  } while (0)
  #define VM_KW() do { if constexpr (KW == 2) { VMW(2); } else { VMW(3); } } while (0)

  const int nt = K / BK_;
  // prologue: tiles 0,1 staged; wait tile0 (leave tile1's KW in flight)
  STAGE(0, 0);
  STAGE(1, BUFSZ);
  VM_KW();
  BAR();

  int rb = 0, sb = 2 * BUFSZ;
  for (int tt = 0; tt < nt; ++tt) {
    bf16x8 af[MR][KR], bq[4][KR];
    #pragma unroll
    for (int mm = 0; mm < MR; ++mm)
      #pragma unroll
      for (int ks = 0; ks < KR; ++ks)
        af[mm][ks] = *(const bf16x8*)(lds + rb + aRd[mm][ks]);
    #pragma unroll
    for (int nf = 0; nf < 4; ++nf)
      #pragma unroll
      for (int ks = 0; ks < KR; ++ks)
        bq[nf][ks] = *(const bf16x8*)(lds + rb + bRd[nf][ks]);
    if (tt + 2 < nt) STAGE(tt + 2, sb);
    // no lgkmcnt(0) drain, no setprio: let the compiler interleave the MFMA
    // cluster with the tail of the ds_read burst via per-register lgkmcnt.
    #pragma unroll
    for (int ks = 0; ks < KR; ++ks)
      #pragma unroll
      for (int mm = 0; mm < MR; ++mm)
        #pragma unroll
        for (int nf = 0; nf < 4; ++nf)
          acc[mm][nf] = __builtin_amdgcn_mfma_f32_16x16x32_bf16(af[mm][ks], bq[nf][ks], acc[mm][nf], 0, 0, 0);
    if (tt + 2 < nt) { VM_KW(); } else { VMW(0); }
    BAR();
    rb = (rb == 2 * BUFSZ) ? 0 : rb + BUFSZ;
    sb = (sb == 2 * BUFSZ) ? 0 : sb + BUFSZ;
  }
  #undef STAGE
  #undef VM_KW

  // epilogue: C/D mapping col=lane&15, row=(lane>>4)*4+reg  [verified m89/m91]
  const long crow0 = m0 + wm * (BM_ / 4) + cs * 4;
  const long ccol0 = n0 + wn * 64 + lr;
  if (MODE == 0) {
    float* C = (float*)g.C + bz * g.sC;
    #pragma unroll
    for (int mm = 0; mm < MR; ++mm)
      #pragma unroll
      for (int nf = 0; nf < 4; ++nf)
        #pragma unroll
        for (int rr = 0; rr < 4; ++rr)
          C[(crow0 + mm * 16 + rr) * g.ldc + ccol0 + nf * 16] = acc[mm][nf][rr];
  } else {
    __hip_bfloat16* C = (__hip_bfloat16*)g.C + bz * g.sC;
    #pragma unroll
    for (int mm = 0; mm < MR; ++mm)
      #pragma unroll
      for (int nf = 0; nf < 4; ++nf)
        #pragma unroll
        for (int rr = 0; rr < 4; ++rr)
          C[(crow0 + mm * 16 + rr) * g.ldc + ccol0 + nf * 16] =
              __float2bfloat16(acc[mm][nf][rr] * g.cscale);
  }
}

// ---------------- row softmax: bf16 scores (pre-scaled) + mask -> bf16 P in place ----------------
__global__ __launch_bounds__(256) void softmax_rows(__hip_bfloat16* __restrict__ S,
                                                    const int* __restrict__ Mask) {
  const long row = blockIdx.x;
  short* srow = (short*)(S + row * 2048);
  const int* mrow = Mask + row * 2048;
  const int t = threadIdx.x;
  const s16x8 sv = *(const s16x8*)(srow + t * 8);
  const int4 q0 = *(const int4*)(mrow + t * 8);
  const int4 q1 = *(const int4*)(mrow + t * 8 + 4);
  float f[8];
  f[0] = q0.x ? bf2f(sv[0]) : -1e20f;
  f[1] = q0.y ? bf2f(sv[1]) : -1e20f;
  f[2] = q0.z ? bf2f(sv[2]) : -1e20f;
  f[3] = q0.w ? bf2f(sv[3]) : -1e20f;
  f[4] = q1.x ? bf2f(sv[4]) : -1e20f;
  f[5] = q1.y ? bf2f(sv[5]) : -1e20f;
  f[6] = q1.z ? bf2f(sv[6]) : -1e20f;
  f[7] = q1.w ? bf2f(sv[7]) : -1e20f;

  float mx = f[0];
  #pragma unroll
  for (int i = 1; i < 8; ++i) mx = fmaxf(mx, f[i]);
  #pragma unroll
  for (int off = 32; off > 0; off >>= 1) mx = fmaxf(mx, __shfl_xor(mx, off));
  __shared__ float redm[4], reds[4];
  if ((t & 63) == 0) redm[t >> 6] = mx;
  __syncthreads();   // also orders all srow reads before the in-place write below
  mx = fmaxf(fmaxf(redm[0], redm[1]), fmaxf(redm[2], redm[3]));

  float e[8];
  float s = 0.f;
  #pragma unroll
  for (int i = 0; i < 8; ++i) { e[i] = __expf(f[i] - mx); s += e[i]; }
  #pragma unroll
  for (int off = 32; off > 0; off >>= 1) s += __shfl_xor(s, off);
  if ((t & 63) == 0) reds[t >> 6] = s;
  __syncthreads();
  s = reds[0] + reds[1] + reds[2] + reds[3];
  const float inv = 1.f / s;

  s16x8 o;
  #pragma unroll
  for (int i = 0; i < 8; ++i) o[i] = (short)f2bf_bits(e[i] * inv);
  *(s16x8*)(srow + t * 8) = o;
}

extern "C" void kernel_launch(void* const* d_in, const int* in_sizes, int n_in,
                              void* d_out, int out_size, void* d_ws, size_t ws_size,
                              hipStream_t stream) {
  const float* x   = (const float*)d_in[0];
  const int*   msk = (const int*)d_in[1];
  const float* Wqk = (const float*)d_in[2];
  const float* Wvc = (const float*)d_in[3];
  float* out = (float*)d_out;
  char* ws = (char*)d_ws;

  // workspace: x_bf16 | q_bf16 (pre-scaled by 1/32) | vT_bf16 | Wqk_bf16 | Wvc_bf16 | S_bf16
  __hip_bfloat16* xb   = (__hip_bfloat16*)(ws + 0);          // 16 MiB
  __hip_bfloat16* qb   = (__hip_bfloat16*)(ws + 16777216);   // 16 MiB
  __hip_bfloat16* vT   = (__hip_bfloat16*)(ws + 33554432);   // 16 MiB
  __hip_bfloat16* wqkb = (__hip_bfloat16*)(ws + 50331648);   // 2 MiB
  __hip_bfloat16* wvcb = (__hip_bfloat16*)(ws + 52428800);   // 2 MiB
  __hip_bfloat16* Sbf  = (__hip_bfloat16*)(ws + 54525952);   // 32 MiB

  cvt_f32_to_bf16<<<8192, 256, 0, stream>>>(x,   xb);
  cvt_f32_to_bf16<<<1024, 256, 0, stream>>>(Wqk, wqkb);
  cvt_f32_to_bf16<<<1024, 256, 0, stream>>>(Wvc, wvcb);

  // grouped: q = (x @ Wqk^T)/32  [8192x1024, 128 tiles]  +  vT[b] = Wvc @ x[b]^T [128 tiles]
  GemmDesc gq{xb,   wqkb, qb, 1024, 1024, 1024, 4, 128, 0L, 0L, 0L, 0.03125f};
  GemmDesc gv{wvcb, xb,   vT, 1024, 1024, 2048, 8, 32, 0L, 2097152L, 2097152L, 1.f};
  gemm16<1, 256, 32><<<dim3(256), 1024, 0, stream>>>(gq, gv, 128, 1024);

  // S[b] = q'[b] @ x[b]^T  (bf16 scores, already scaled)
  GemmDesc gs{qb, xb, Sbf, 1024, 1024, 2048, 8, 64, 2097152L, 2097152L, 4194304L, 1.f};
  gemm16<1, 256, 32><<<dim3(256), 1024, 0, stream>>>(gs, gs, 256, 1024);

  // softmax rows: bf16+mask -> bf16 P in place (stride 2048)
  softmax_rows<<<dim3(8192), 256, 0, stream>>>(Sbf, msk);

  // out[b] = P[b] @ vT[b]^T  (K=2048, fp32 out), BM=128/BK=64 variant -> grid 256
  GemmDesc go{Sbf, vT, out, 2048, 2048, 1024, 4, 64, 4194304L, 2097152L, 2097152L, 1.f};
  gemm16<0, 128, 64><<<dim3(256), 1024, 0, stream>>>(go, go, 256, 2048);
}